// Round 7
// baseline (1460.197 us; speedup 1.0000x reference)
//
#include <hip/hip_runtime.h>

#define NN 200000
#define NE 5000000
#define DIN 128
#define HID 16
#define DOUT 2
#define BSH 9            // dst-buckets of 512 nodes
#define BSZ 512
#define NB 391           // ceil(NN/512)
#define NCH 8            // src slices of 25000 nodes (1.6 MB of xs' @ HID=16)
#define SLICE_DIV 25000
#define NK (NB * NCH)    // 3128 sort keys
#define PB 128           // partition grid blocks
#define PT 512           // partition block threads

static_assert((NN + BSZ - 1) / BSZ == NB, "bucket count");
static_assert((NN - 1) / SLICE_DIV == NCH - 1, "slice count");

// ---------------- edge partition: counting sort by (dst>>9, src/25000) ----------------

__global__ __launch_bounds__(PT) void hist_pass(const int* __restrict__ src,
                                                const int* __restrict__ dst,
                                                int* __restrict__ blockHist) {
    __shared__ int h[NK];  // 12.5 KB
    for (int k = threadIdx.x; k < NK; k += PT) h[k] = 0;
    __syncthreads();
    for (int i = blockIdx.x * PT + threadIdx.x; i < NE; i += PB * PT) {
        int key = ((dst[i] >> BSH) << 3) + src[i] / SLICE_DIV;
        atomicAdd(&h[key], 1);
    }
    __syncthreads();
    for (int k = threadIdx.x; k < NK; k += PT)
        blockHist[(size_t)blockIdx.x * NK + k] = h[k];
}

__global__ __launch_bounds__(1024) void scan_pass(int* __restrict__ blockHist,
                                                  int* __restrict__ chunkStart) {
    __shared__ int tot[NK];     // 12.5 KB
    __shared__ int psum[1024];
    int t = threadIdx.x;
    for (int k = t; k < NK; k += 1024) {
        int s = 0;
        for (int b = 0; b < PB; ++b) s += blockHist[(size_t)b * NK + k];
        tot[k] = s;
    }
    __syncthreads();
    const int KPT = (NK + 1023) / 1024;  // 4
    int k0 = t * KPT; if (k0 > NK) k0 = NK;
    int k1 = k0 + KPT; if (k1 > NK) k1 = NK;
    int s = 0;
    for (int k = k0; k < k1; ++k) s += tot[k];
    psum[t] = s;
    __syncthreads();
    if (t == 0) {
        int car = 0;
        for (int i = 0; i < 1024; ++i) { int v = psum[i]; psum[i] = car; car += v; }
    }
    __syncthreads();
    {
        int run = psum[t];
        for (int k = k0; k < k1; ++k) { int v = tot[k]; tot[k] = run; run += v; }
    }
    __syncthreads();
    for (int k = t; k < NK; k += 1024) {
        int r = tot[k];
        for (int b = 0; b < PB; ++b) {
            size_t idx = (size_t)b * NK + k;
            int v = blockHist[idx];
            blockHist[idx] = r;
            r += v;
        }
    }
    for (int k = t; k < NK; k += 1024) chunkStart[k] = tot[k];
    if (t == 0) chunkStart[NK] = NE;
}

__global__ __launch_bounds__(PT) void scatter_pass(const int* __restrict__ src,
                                                   const int* __restrict__ dst,
                                                   const int* __restrict__ blockHist,
                                                   unsigned* __restrict__ pedge) {
    __shared__ int cur[NK];  // 12.5 KB
    for (int k = threadIdx.x; k < NK; k += PT)
        cur[k] = blockHist[(size_t)blockIdx.x * NK + k];
    __syncthreads();
    // MUST traverse edges in the same per-block order as hist_pass
    for (int i = blockIdx.x * PT + threadIdx.x; i < NE; i += PB * PT) {
        int sv = src[i], dv = dst[i];
        int key = ((dv >> BSH) << 3) + sv / SLICE_DIV;
        int pos = atomicAdd(&cur[key], 1);  // LDS atomic only
        pedge[pos] = ((unsigned)sv << BSH) | (unsigned)(dv & (BSZ - 1));
    }
}

__global__ __launch_bounds__(BSZ) void deg_dis(const unsigned* __restrict__ pedge,
                                               const int* __restrict__ chunkStart,
                                               float* __restrict__ dis) {
    __shared__ int cnt[BSZ];
    int t = threadIdx.x;
    cnt[t] = 1;  // self loop
    __syncthreads();
    int e0 = chunkStart[blockIdx.x * NCH], e1 = chunkStart[(blockIdx.x + 1) * NCH];
    for (int e = e0 + t; e < e1; e += BSZ) atomicAdd(&cnt[pedge[e] & (BSZ - 1u)], 1);
    __syncthreads();
    int node = (blockIdx.x << BSH) + t;
    if (node < NN) dis[node] = rsqrtf((float)cnt[t]);
}

// ---------------- dense GEMMs, epilogue-scaled by dis[row] (xs' = (h@W)*dis) ----------------

__global__ __launch_bounds__(256) void gemm_x_w1(const float* __restrict__ x,
                                                 const float* __restrict__ W,
                                                 const float* __restrict__ dis,
                                                 float* __restrict__ out) {
    __shared__ float w[DIN * HID];
    for (int t = threadIdx.x; t < DIN * HID; t += 256) w[t] = W[t];
    __syncthreads();
    int row = blockIdx.x * 16 + (threadIdx.x >> 4);
    int c = threadIdx.x & 15;
    if (row >= NN) return;
    const float4* xr = reinterpret_cast<const float4*>(x + (size_t)row * DIN);
    float acc = 0.f;
#pragma unroll
    for (int k4 = 0; k4 < DIN / 4; ++k4) {
        float4 v = xr[k4];
        acc += v.x * w[(4 * k4 + 0) * HID + c] + v.y * w[(4 * k4 + 1) * HID + c]
             + v.z * w[(4 * k4 + 2) * HID + c] + v.w * w[(4 * k4 + 3) * HID + c];
    }
    out[row * HID + c] = acc * dis[row];
}

__global__ __launch_bounds__(256) void gemm_h_w16(const float* __restrict__ h,
                                                  const float* __restrict__ W,
                                                  const float* __restrict__ dis,
                                                  float* __restrict__ out) {
    __shared__ float w[HID * HID];
    if (threadIdx.x < HID * HID) w[threadIdx.x] = W[threadIdx.x];
    __syncthreads();
    int row = blockIdx.x * 16 + (threadIdx.x >> 4);
    int c = threadIdx.x & 15;
    if (row >= NN) return;
    const float4* hr = reinterpret_cast<const float4*>(h + (size_t)row * HID);
    float acc = 0.f;
#pragma unroll
    for (int k4 = 0; k4 < HID / 4; ++k4) {
        float4 v = hr[k4];
        acc += v.x * w[(4 * k4 + 0) * HID + c] + v.y * w[(4 * k4 + 1) * HID + c]
             + v.z * w[(4 * k4 + 2) * HID + c] + v.w * w[(4 * k4 + 3) * HID + c];
    }
    out[row * HID + c] = acc * dis[row];
}

__global__ __launch_bounds__(256) void gemm_h_w2(const float* __restrict__ h,
                                                 const float* __restrict__ W,
                                                 const float* __restrict__ dis,
                                                 float* __restrict__ out) {
    int t = blockIdx.x * 256 + threadIdx.x;
    int row = t >> 1;
    int c = t & 1;
    if (row >= NN) return;
    const float* hr = h + (size_t)row * HID;
    float acc = 0.f;
#pragma unroll
    for (int k = 0; k < HID; ++k) acc += hr[k] * W[k * DOUT + c];
    out[row * DOUT + c] = acc * dis[row];
}

// ---------------- aggregation: one launch per src-slice (launch = global sync) ----------------

// Round r: every block gathers ONLY from xs'[slice r] (1.6 MB -> L2-resident on
// every XCD). Block b owns dst-stripe [b*512, (b+1)*512) exclusively; partial
// sums accumulate in buf across rounds via plain read-modify-write.
__global__ __launch_bounds__(1024) void agg16_round(const unsigned* __restrict__ pedge,
                                                    const int* __restrict__ chunkStart,
                                                    const float* __restrict__ xs,
                                                    const float* __restrict__ dis,
                                                    const float* __restrict__ bias,
                                                    float* __restrict__ buf,
                                                    int r, int relu) {
    __shared__ float acc[BSZ * HID];  // 32 KB
    int t = threadIdx.x;
    int b = blockIdx.x;
    int base = b << BSH;
    if (r == 0) {  // self-loop row: raw xs'[node]
        for (int i = t; i < BSZ * HID; i += 1024) {
            int gi = (base << 4) + i;
            acc[i] = (gi < NN * HID) ? xs[gi] : 0.f;
        }
    } else {
        for (int i = t; i < BSZ * HID; i += 1024) acc[i] = 0.f;
    }
    __syncthreads();
    int e0 = chunkStart[b * NCH + r], e1 = chunkStart[b * NCH + r + 1];
    int c = t & 15;
    const int NS = 64;  // edge streams
    int e = e0 + (t >> 4);
    for (; e + 3 * NS < e1; e += 4 * NS) {
        unsigned p0 = pedge[e];
        unsigned p1 = pedge[e + NS];
        unsigned p2 = pedge[e + 2 * NS];
        unsigned p3 = pedge[e + 3 * NS];
        float v0 = xs[((p0 >> BSH) << 4) + c];
        float v1 = xs[((p1 >> BSH) << 4) + c];
        float v2 = xs[((p2 >> BSH) << 4) + c];
        float v3 = xs[((p3 >> BSH) << 4) + c];
        atomicAdd(&acc[((p0 & (BSZ - 1u)) << 4) + c], v0);
        atomicAdd(&acc[((p1 & (BSZ - 1u)) << 4) + c], v1);
        atomicAdd(&acc[((p2 & (BSZ - 1u)) << 4) + c], v2);
        atomicAdd(&acc[((p3 & (BSZ - 1u)) << 4) + c], v3);
    }
    for (; e < e1; e += NS) {
        unsigned p = pedge[e];
        atomicAdd(&acc[((p & (BSZ - 1u)) << 4) + c], xs[((p >> BSH) << 4) + c]);
    }
    __syncthreads();
    if (r == 0) {
        for (int i = t; i < BSZ * HID; i += 1024) {
            int gi = (base << 4) + i;
            if (gi < NN * HID) buf[gi] = acc[i];
        }
    } else if (r < NCH - 1) {
        for (int i = t; i < BSZ * HID; i += 1024) {
            int gi = (base << 4) + i;
            if (gi < NN * HID) buf[gi] += acc[i];
        }
    } else {  // last round: epilogue  out = relu(dis[dst]*(sum) + bias)
        for (int i = t; i < BSZ * HID; i += 1024) {
            int gi = (base << 4) + i;
            if (gi < NN * HID) {
                int node = base + (i >> 4);
                float v = dis[node] * (buf[gi] + acc[i]) + bias[i & 15];
                buf[gi] = relu ? fmaxf(v, 0.f) : v;
            }
        }
    }
}

// conv2 aggregation + bias + log_softmax; table is 1.6 MB -> L2-resident, single pass.
__global__ __launch_bounds__(1024) void agg2_lsm(const unsigned* __restrict__ pedge,
                                                 const int* __restrict__ chunkStart,
                                                 const float* __restrict__ dis,
                                                 const float* __restrict__ xs,
                                                 const float* __restrict__ bias,
                                                 float* __restrict__ out) {
    __shared__ float acc[BSZ * DOUT];
    int t = threadIdx.x;
    int base = blockIdx.x << BSH;
    if (t < BSZ) {
        int node = base + t;
        if (node < NN) {  // self-loop raw row
            float2 v = reinterpret_cast<const float2*>(xs)[node];
            acc[t * 2 + 0] = v.x;
            acc[t * 2 + 1] = v.y;
        } else {
            acc[t * 2 + 0] = 0.f;
            acc[t * 2 + 1] = 0.f;
        }
    }
    __syncthreads();
    int e0 = chunkStart[blockIdx.x * NCH], e1 = chunkStart[(blockIdx.x + 1) * NCH];
    int c = t & 1;
    const int NS = 512;
    int e = e0 + (t >> 1);
    for (; e + 3 * NS < e1; e += 4 * NS) {
        unsigned p0 = pedge[e];
        unsigned p1 = pedge[e + NS];
        unsigned p2 = pedge[e + 2 * NS];
        unsigned p3 = pedge[e + 3 * NS];
        float v0 = xs[(p0 >> BSH) * 2 + c];
        float v1 = xs[(p1 >> BSH) * 2 + c];
        float v2 = xs[(p2 >> BSH) * 2 + c];
        float v3 = xs[(p3 >> BSH) * 2 + c];
        atomicAdd(&acc[(p0 & (BSZ - 1u)) * 2 + c], v0);
        atomicAdd(&acc[(p1 & (BSZ - 1u)) * 2 + c], v1);
        atomicAdd(&acc[(p2 & (BSZ - 1u)) * 2 + c], v2);
        atomicAdd(&acc[(p3 & (BSZ - 1u)) * 2 + c], v3);
    }
    for (; e < e1; e += NS) {
        unsigned p = pedge[e];
        atomicAdd(&acc[(p & (BSZ - 1u)) * 2 + c], xs[(p >> BSH) * 2 + c]);
    }
    __syncthreads();
    if (t < BSZ) {
        int node = base + t;
        if (node < NN) {
            float d = dis[node];
            float v0 = acc[t * 2 + 0] * d + bias[0];
            float v1 = acc[t * 2 + 1] * d + bias[1];
            float m = fmaxf(v0, v1);
            float lse = m + logf(__expf(v0 - m) + __expf(v1 - m));
            reinterpret_cast<float2*>(out)[node] = make_float2(v0 - lse, v1 - lse);
        }
    }
}

// ---------------- launch ----------------

extern "C" void kernel_launch(void* const* d_in, const int* in_sizes, int n_in,
                              void* d_out, int out_size, void* d_ws, size_t ws_size,
                              hipStream_t stream) {
    const float* x = (const float*)d_in[0];
    const int* ei = (const int*)d_in[1];
    const float* W1 = (const float*)d_in[2];
    const float* b1 = (const float*)d_in[3];
    const float* W3 = (const float*)d_in[4];
    const float* b3 = (const float*)d_in[5];
    const float* W2 = (const float*)d_in[6];
    const float* b2 = (const float*)d_in[7];
    float* out = (float*)d_out;

    const int* src = ei;       // edge_index[0]
    const int* dst = ei + NE;  // edge_index[1]

    // workspace layout (~48 MB)
    char* ws = (char*)d_ws;
    unsigned* pedge = (unsigned*)ws;                      // NE          (20 MB)
    int* blockHist = (int*)(ws + sizeof(unsigned) * NE);  // PB*NK       (1.6 MB)
    int* chunkStart = blockHist + (size_t)PB * NK;        // NK+1
    float* dis = (float*)(chunkStart + NK + 1);           // NN
    float* bufA = dis + NN;                               // NN*HID      (12.8 MB)
    float* bufB = bufA + NN * HID;                        // NN*HID      (12.8 MB)

    const int B = 256;
    auto cdiv = [](long long a, long long b) { return (int)((a + b - 1) / b); };

    // partition + normalization
    hist_pass<<<PB, PT, 0, stream>>>(src, dst, blockHist);
    scan_pass<<<1, 1024, 0, stream>>>(blockHist, chunkStart);
    scatter_pass<<<PB, PT, 0, stream>>>(src, dst, blockHist, pedge);
    deg_dis<<<NB, BSZ, 0, stream>>>(pedge, chunkStart, dis);

    // conv1: bufA = (x@W1)*dis ; 8 slice-rounds into bufB (relu+bias in last)
    gemm_x_w1<<<cdiv(NN, 16), B, 0, stream>>>(x, W1, dis, bufA);
    for (int r = 0; r < NCH; ++r)
        agg16_round<<<NB, 1024, 0, stream>>>(pedge, chunkStart, bufA, dis, b1, bufB, r, 1);

    // conv3
    gemm_h_w16<<<cdiv(NN, 16), B, 0, stream>>>(bufB, W3, dis, bufA);
    for (int r = 0; r < NCH; ++r)
        agg16_round<<<NB, 1024, 0, stream>>>(pedge, chunkStart, bufA, dis, b3, bufB, r, 1);

    // conv2 + log_softmax
    gemm_h_w2<<<cdiv((long long)NN * DOUT, B), B, 0, stream>>>(bufB, W2, dis, bufA);
    agg2_lsm<<<NB, 1024, 0, stream>>>(pedge, chunkStart, dis, bufA, b2, out);
}

// Round 8
// 520.217 us; speedup vs baseline: 2.8069x; 2.8069x over previous
//
#include <hip/hip_runtime.h>

#define NN 200000
#define NE 5000000
#define DIN 128
#define HID 16
#define DOUT 2
#define BSH 9            // dst-buckets of 512 nodes
#define BSZ 512
#define NB 391           // ceil(NN/512)
#define NCH 8            // src slices of 25000 nodes (1.6 MB of xs' @ HID=16)
#define SLICE_DIV 25000
#define NK (NB * NCH)    // 3128 sort keys
#define PB 256           // partition grid blocks
#define PT 512           // partition block threads
#define CAP 4096         // max edges per (bucket,slice) segment; mean 1599, 62 sigma

static_assert((NN + BSZ - 1) / BSZ == NB, "bucket count");
static_assert((NN - 1) / SLICE_DIV == NCH - 1, "slice count");

// ---------------- stage 1: counting sort by (dst>>9, src/25000) ----------------

__global__ __launch_bounds__(PT) void hist_pass(const int* __restrict__ src,
                                                const int* __restrict__ dst,
                                                int* __restrict__ blockHist) {
    __shared__ int h[NK];  // 12.5 KB
    for (int k = threadIdx.x; k < NK; k += PT) h[k] = 0;
    __syncthreads();
    for (int i = blockIdx.x * PT + threadIdx.x; i < NE; i += PB * PT) {
        int key = ((dst[i] >> BSH) << 3) + src[i] / SLICE_DIV;
        atomicAdd(&h[key], 1);
    }
    __syncthreads();
    for (int k = threadIdx.x; k < NK; k += PT)
        blockHist[(size_t)blockIdx.x * NK + k] = h[k];
}

__global__ __launch_bounds__(1024) void scan_pass(int* __restrict__ blockHist,
                                                  int* __restrict__ chunkStart) {
    __shared__ int tot[NK];     // 12.5 KB
    __shared__ int psum[1024];
    int t = threadIdx.x;
    for (int k = t; k < NK; k += 1024) {
        int s = 0;
        for (int b = 0; b < PB; ++b) s += blockHist[(size_t)b * NK + k];
        tot[k] = s;
    }
    __syncthreads();
    const int KPT = (NK + 1023) / 1024;  // 4
    int k0 = t * KPT; if (k0 > NK) k0 = NK;
    int k1 = k0 + KPT; if (k1 > NK) k1 = NK;
    int s = 0;
    for (int k = k0; k < k1; ++k) s += tot[k];
    psum[t] = s;
    __syncthreads();
    if (t == 0) {
        int car = 0;
        for (int i = 0; i < 1024; ++i) { int v = psum[i]; psum[i] = car; car += v; }
    }
    __syncthreads();
    {
        int run = psum[t];
        for (int k = k0; k < k1; ++k) { int v = tot[k]; tot[k] = run; run += v; }
    }
    __syncthreads();
    for (int k = t; k < NK; k += 1024) {
        int r = tot[k];
        for (int b = 0; b < PB; ++b) {
            size_t idx = (size_t)b * NK + k;
            int v = blockHist[idx];
            blockHist[idx] = r;
            r += v;
        }
    }
    for (int k = t; k < NK; k += 1024) chunkStart[k] = tot[k];
    if (t == 0) chunkStart[NK] = NE;
}

__global__ __launch_bounds__(PT) void scatter_pass(const int* __restrict__ src,
                                                   const int* __restrict__ dst,
                                                   const int* __restrict__ blockHist,
                                                   unsigned* __restrict__ pedge) {
    __shared__ int cur[NK];  // 12.5 KB
    for (int k = threadIdx.x; k < NK; k += PT)
        cur[k] = blockHist[(size_t)blockIdx.x * NK + k];
    __syncthreads();
    // MUST traverse edges in the same per-block order as hist_pass
    for (int i = blockIdx.x * PT + threadIdx.x; i < NE; i += PB * PT) {
        int sv = src[i], dv = dst[i];
        int key = ((dv >> BSH) << 3) + sv / SLICE_DIV;
        int pos = atomicAdd(&cur[key], 1);  // LDS atomic only
        pedge[pos] = ((unsigned)sv << BSH) | (unsigned)(dv & (BSZ - 1));
    }
}

// ---------------- stage 2: within-segment sort by dst -> CSR (one-time) ----------------
// Produces pedge2[e] = src (row-sorted within each (bucket,slice) segment),
// rowStart[seg*512 + d] = absolute start of row d in segment seg, and dis[].

__global__ __launch_bounds__(512) void subsort(const unsigned* __restrict__ pedge,
                                               const int* __restrict__ chunkStart,
                                               int* __restrict__ pedge2,
                                               int* __restrict__ rowStart,
                                               float* __restrict__ dis) {
    __shared__ unsigned ebuf[CAP];  // 16 KB
    __shared__ int hist[BSZ];
    __shared__ int cur[BSZ];
    __shared__ int deg[BSZ];
    int t = threadIdx.x;
    int b = blockIdx.x;
    deg[t] = 1;  // self loop
    for (int s = 0; s < NCH; ++s) {
        int seg = b * NCH + s;
        int e0 = chunkStart[seg], e1 = chunkStart[seg + 1];
        int n = e1 - e0;
        hist[t] = 0;
        __syncthreads();
        for (int i = t; i < n; i += 512) {
            unsigned p = pedge[e0 + i];
            ebuf[i] = p;
            atomicAdd(&hist[p & (BSZ - 1u)], 1);
        }
        __syncthreads();
        int v = hist[t];
        deg[t] += v;
        cur[t] = v;  // inclusive scan below
        __syncthreads();
        for (int off = 1; off < BSZ; off <<= 1) {
            int add = (t >= off) ? cur[t - off] : 0;
            __syncthreads();
            cur[t] += add;
            __syncthreads();
        }
        int excl = cur[t] - v;
        rowStart[seg * BSZ + t] = e0 + excl;
        cur[t] = excl;
        __syncthreads();
        for (int i = t; i < n; i += 512) {
            unsigned p = ebuf[i];
            int d = p & (BSZ - 1u);
            int pos = atomicAdd(&cur[d], 1);  // 1 int LDS atomic per edge, one-time
            pedge2[e0 + pos] = (int)(p >> BSH);
        }
        __syncthreads();
    }
    int node = (b << BSH) + t;
    if (node < NN) dis[node] = rsqrtf((float)deg[t]);
    if (b == 0 && t == 0) rowStart[NK * BSZ] = NE;
}

// ---------------- dense GEMMs, epilogue-scaled by dis[row] (xs' = (h@W)*dis) ----------------

__global__ __launch_bounds__(256) void gemm_x_w1(const float* __restrict__ x,
                                                 const float* __restrict__ W,
                                                 const float* __restrict__ dis,
                                                 float* __restrict__ out) {
    __shared__ float w[DIN * HID];
    for (int t = threadIdx.x; t < DIN * HID; t += 256) w[t] = W[t];
    __syncthreads();
    int row = blockIdx.x * 16 + (threadIdx.x >> 4);
    int c = threadIdx.x & 15;
    if (row >= NN) return;
    const float4* xr = reinterpret_cast<const float4*>(x + (size_t)row * DIN);
    float acc = 0.f;
#pragma unroll
    for (int k4 = 0; k4 < DIN / 4; ++k4) {
        float4 v = xr[k4];
        acc += v.x * w[(4 * k4 + 0) * HID + c] + v.y * w[(4 * k4 + 1) * HID + c]
             + v.z * w[(4 * k4 + 2) * HID + c] + v.w * w[(4 * k4 + 3) * HID + c];
    }
    out[row * HID + c] = acc * dis[row];
}

__global__ __launch_bounds__(256) void gemm_h_w16(const float* __restrict__ h,
                                                  const float* __restrict__ W,
                                                  const float* __restrict__ dis,
                                                  float* __restrict__ out) {
    __shared__ float w[HID * HID];
    if (threadIdx.x < HID * HID) w[threadIdx.x] = W[threadIdx.x];
    __syncthreads();
    int row = blockIdx.x * 16 + (threadIdx.x >> 4);
    int c = threadIdx.x & 15;
    if (row >= NN) return;
    const float4* hr = reinterpret_cast<const float4*>(h + (size_t)row * HID);
    float acc = 0.f;
#pragma unroll
    for (int k4 = 0; k4 < HID / 4; ++k4) {
        float4 v = hr[k4];
        acc += v.x * w[(4 * k4 + 0) * HID + c] + v.y * w[(4 * k4 + 1) * HID + c]
             + v.z * w[(4 * k4 + 2) * HID + c] + v.w * w[(4 * k4 + 3) * HID + c];
    }
    out[row * HID + c] = acc * dis[row];
}

__global__ __launch_bounds__(256) void gemm_h_w2(const float* __restrict__ h,
                                                 const float* __restrict__ W,
                                                 const float* __restrict__ dis,
                                                 float* __restrict__ out) {
    int t = blockIdx.x * 256 + threadIdx.x;
    int row = t >> 1;
    int c = t & 1;
    if (row >= NN) return;
    const float* hr = h + (size_t)row * HID;
    float acc = 0.f;
#pragma unroll
    for (int k = 0; k < HID; ++k) acc += hr[k] * W[k * DOUT + c];
    out[row * DOUT + c] = acc * dis[row];
}

// ---------------- aggregation: CSR register accumulation, ZERO atomics ----------------
// Round r: 4-lane groups; lane c4 owns a float4 quarter-row. Gathers confined to
// src slice r (1.6 MB window, L2-resident). Exclusive dst ownership -> plain RMW.

__global__ __launch_bounds__(1024) void agg16_round(const int* __restrict__ pedge2,
                                                    const int* __restrict__ rowStart,
                                                    const float* __restrict__ xs,
                                                    const float* __restrict__ dis,
                                                    const float* __restrict__ bias,
                                                    float* __restrict__ buf,
                                                    int r, int relu) {
    int t = threadIdx.x;
    int b = blockIdx.x;
    int base = b << BSH;
    int c4 = t & 3;
    int g = t >> 2;  // 256 row-groups
    const int* rs = rowStart + (size_t)(b * NCH + r) * BSZ;
    const float4* xs4 = reinterpret_cast<const float4*>(xs);
    float4* buf4 = reinterpret_cast<float4*>(buf);
    for (int d = g; d < BSZ; d += 256) {
        int e0 = rs[d];
        int e1 = rs[d + 1];  // d=511 reads next segment's start: contiguous layout
        float ax = 0.f, ay = 0.f, az = 0.f, aw = 0.f;
        int e = e0;
        for (; e + 1 < e1; e += 2) {
            int s0 = pedge2[e], s1 = pedge2[e + 1];
            float4 u = xs4[(s0 << 2) + c4];
            float4 w = xs4[(s1 << 2) + c4];
            ax += u.x + w.x; ay += u.y + w.y; az += u.z + w.z; aw += u.w + w.w;
        }
        if (e < e1) {
            float4 u = xs4[(pedge2[e] << 2) + c4];
            ax += u.x; ay += u.y; az += u.z; aw += u.w;
        }
        int node = base + d;
        if (node < NN) {
            int gi = (node << 2) + c4;
            if (r == 0) {  // self-loop row (xs' already has dis[src] factor)
                float4 u = xs4[gi];
                buf4[gi] = make_float4(ax + u.x, ay + u.y, az + u.z, aw + u.w);
            } else if (r < NCH - 1) {
                float4 u = buf4[gi];
                buf4[gi] = make_float4(ax + u.x, ay + u.y, az + u.z, aw + u.w);
            } else {  // epilogue: out = relu(dis[dst]*sum + bias)
                float4 u = buf4[gi];
                float dd = dis[node];
                float4 bb = reinterpret_cast<const float4*>(bias)[c4];
                float vx = dd * (u.x + ax) + bb.x;
                float vy = dd * (u.y + ay) + bb.y;
                float vz = dd * (u.z + az) + bb.z;
                float vw = dd * (u.w + aw) + bb.w;
                if (relu) {
                    vx = fmaxf(vx, 0.f); vy = fmaxf(vy, 0.f);
                    vz = fmaxf(vz, 0.f); vw = fmaxf(vw, 0.f);
                }
                buf4[gi] = make_float4(vx, vy, vz, vw);
            }
        }
    }
}

// conv2: one thread per dst row, float2 registers, fused bias + log_softmax.
__global__ __launch_bounds__(512) void agg2_lsm(const int* __restrict__ pedge2,
                                                const int* __restrict__ rowStart,
                                                const float* __restrict__ xs,
                                                const float* __restrict__ dis,
                                                const float* __restrict__ bias,
                                                float* __restrict__ out) {
    int t = threadIdx.x;
    int b = blockIdx.x;
    int node = (b << BSH) + t;
    if (node >= NN) return;
    const float2* xs2 = reinterpret_cast<const float2*>(xs);
    float a0 = 0.f, a1 = 0.f;
    for (int s = 0; s < NCH; ++s) {
        const int* rs = rowStart + (size_t)(b * NCH + s) * BSZ;
        int e0 = rs[t], e1 = rs[t + 1];
        for (int e = e0; e < e1; ++e) {
            float2 v = xs2[pedge2[e]];
            a0 += v.x; a1 += v.y;
        }
    }
    float2 sv = xs2[node];
    float d = dis[node];
    float v0 = (a0 + sv.x) * d + bias[0];
    float v1 = (a1 + sv.y) * d + bias[1];
    float m = fmaxf(v0, v1);
    float lse = m + logf(__expf(v0 - m) + __expf(v1 - m));
    reinterpret_cast<float2*>(out)[node] = make_float2(v0 - lse, v1 - lse);
}

// ---------------- launch ----------------

extern "C" void kernel_launch(void* const* d_in, const int* in_sizes, int n_in,
                              void* d_out, int out_size, void* d_ws, size_t ws_size,
                              hipStream_t stream) {
    const float* x = (const float*)d_in[0];
    const int* ei = (const int*)d_in[1];
    const float* W1 = (const float*)d_in[2];
    const float* b1 = (const float*)d_in[3];
    const float* W3 = (const float*)d_in[4];
    const float* b3 = (const float*)d_in[5];
    const float* W2 = (const float*)d_in[6];
    const float* b2 = (const float*)d_in[7];
    float* out = (float*)d_out;

    const int* src = ei;       // edge_index[0]
    const int* dst = ei + NE;  // edge_index[1]

    // workspace layout (int elements), ~63 MB total. bufA aliases pedge
    // (pedge is dead after subsort; gemm_x_w1 runs after subsort).
    int* W = (int*)d_ws;
    unsigned* pedge = (unsigned*)W;                        // NE
    int* pedge2 = W + NE;                                  // NE
    int* rowStart = W + 2 * (size_t)NE;                    // NK*BSZ + 4 (pad)
    int* blockHist = rowStart + (size_t)NK * BSZ + 4;      // PB*NK
    int* chunkStart = blockHist + (size_t)PB * NK;         // NK + 4 (pad)
    float* dis = (float*)(chunkStart + NK + 4);            // NN
    float* bufB = dis + NN;                                // NN*HID
    float* bufA = (float*)W;                               // aliases pedge (12.8 <= 20 MB)

    const int B = 256;
    auto cdiv = [](long long a, long long b) { return (int)((a + b - 1) / b); };

    // partition: (bucket,slice) sort -> within-segment dst sort -> CSR + dis
    hist_pass<<<PB, PT, 0, stream>>>(src, dst, blockHist);
    scan_pass<<<1, 1024, 0, stream>>>(blockHist, chunkStart);
    scatter_pass<<<PB, PT, 0, stream>>>(src, dst, blockHist, pedge);
    subsort<<<NB, 512, 0, stream>>>(pedge, chunkStart, pedge2, rowStart, dis);

    // conv1: bufA = (x@W1)*dis ; 8 slice-rounds into bufB (relu+bias in last)
    gemm_x_w1<<<cdiv(NN, 16), B, 0, stream>>>(x, W1, dis, bufA);
    for (int r = 0; r < NCH; ++r)
        agg16_round<<<NB, 1024, 0, stream>>>(pedge2, rowStart, bufA, dis, b1, bufB, r, 1);

    // conv3
    gemm_h_w16<<<cdiv(NN, 16), B, 0, stream>>>(bufB, W3, dis, bufA);
    for (int r = 0; r < NCH; ++r)
        agg16_round<<<NB, 1024, 0, stream>>>(pedge2, rowStart, bufA, dis, b3, bufB, r, 1);

    // conv2 + log_softmax
    gemm_h_w2<<<cdiv((long long)NN * DOUT, B), B, 0, stream>>>(bufB, W2, dis, bufA);
    agg2_lsm<<<NB, 512, 0, stream>>>(pedge2, rowStart, bufA, dis, b2, out);
}

// Round 9
// 405.090 us; speedup vs baseline: 3.6046x; 1.2842x over previous
//
#include <hip/hip_runtime.h>

#define NN 200000
#define NE 5000000
#define DIN 128
#define HID 16
#define DOUT 2
#define BSH 9            // dst-buckets of 512 nodes
#define BSZ 512
#define NB 391           // ceil(NN/512)
#define NCH 8            // src slices of 25000 nodes (1.6 MB of xs' @ HID=16)
#define SLICE_DIV 25000
#define NK (NB * NCH)    // 3128 sort keys
#define PB 256           // partition grid blocks
#define PT 512           // partition block threads
#define CAP 4096         // max edges per (bucket,slice) segment; mean 1599, 62 sigma

static_assert((NN + BSZ - 1) / BSZ == NB, "bucket count");
static_assert((NN - 1) / SLICE_DIV == NCH - 1, "slice count");

// ---------------- stage 1: counting sort by (dst>>9, src/25000) ----------------

__global__ __launch_bounds__(PT) void hist_pass(const int* __restrict__ src,
                                                const int* __restrict__ dst,
                                                int* __restrict__ blockHist) {
    __shared__ int h[NK];  // 12.5 KB
    for (int k = threadIdx.x; k < NK; k += PT) h[k] = 0;
    __syncthreads();
    for (int i = blockIdx.x * PT + threadIdx.x; i < NE; i += PB * PT) {
        int key = ((dst[i] >> BSH) << 3) + src[i] / SLICE_DIV;
        atomicAdd(&h[key], 1);
    }
    __syncthreads();
    for (int k = threadIdx.x; k < NK; k += PT)
        blockHist[(size_t)blockIdx.x * NK + k] = h[k];
}

// per-key totals -> chunkStart[k] (unscanned)
__global__ __launch_bounds__(256) void tot_pass(const int* __restrict__ blockHist,
                                                int* __restrict__ chunkStart) {
    int k = blockIdx.x * 256 + threadIdx.x;
    if (k >= NK) return;
    int s = 0;
#pragma unroll 8
    for (int b = 0; b < PB; ++b) s += blockHist[(size_t)b * NK + k];
    chunkStart[k] = s;
}

// exclusive scan of chunkStart[0..NK) in place (single block)
__global__ __launch_bounds__(1024) void scan_keys(int* __restrict__ chunkStart) {
    __shared__ int psum[1024];
    int t = threadIdx.x;
    const int KPT = (NK + 1023) / 1024;  // 4
    int k0 = t * KPT; if (k0 > NK) k0 = NK;
    int k1 = k0 + KPT; if (k1 > NK) k1 = NK;
    int vals[4];
    int s = 0;
    for (int k = k0; k < k1; ++k) { vals[k - k0] = chunkStart[k]; s += vals[k - k0]; }
    psum[t] = s;
    __syncthreads();
    // Hillis-Steele inclusive scan over 1024 partials
    for (int off = 1; off < 1024; off <<= 1) {
        int add = (t >= off) ? psum[t - off] : 0;
        __syncthreads();
        psum[t] += add;
        __syncthreads();
    }
    int run = psum[t] - s;  // exclusive prefix for this thread's range
    for (int k = k0; k < k1; ++k) { chunkStart[k] = run; run += vals[k - k0]; }
    if (t == 0) chunkStart[NK] = NE;
}

// per-(key, block) exclusive offsets into blockHist, using scanned chunkStart
__global__ __launch_bounds__(256) void offsets_pass(int* __restrict__ blockHist,
                                                    const int* __restrict__ chunkStart) {
    int k = blockIdx.x * 256 + threadIdx.x;
    if (k >= NK) return;
    int r = chunkStart[k];
#pragma unroll 8
    for (int b = 0; b < PB; ++b) {
        size_t idx = (size_t)b * NK + k;
        int v = blockHist[idx];
        blockHist[idx] = r;
        r += v;
    }
}

__global__ __launch_bounds__(PT) void scatter_pass(const int* __restrict__ src,
                                                   const int* __restrict__ dst,
                                                   const int* __restrict__ blockHist,
                                                   unsigned* __restrict__ pedge) {
    __shared__ int cur[NK];  // 12.5 KB
    for (int k = threadIdx.x; k < NK; k += PT)
        cur[k] = blockHist[(size_t)blockIdx.x * NK + k];
    __syncthreads();
    // MUST traverse edges in the same per-block order as hist_pass
    for (int i = blockIdx.x * PT + threadIdx.x; i < NE; i += PB * PT) {
        int sv = src[i], dv = dst[i];
        int key = ((dv >> BSH) << 3) + sv / SLICE_DIV;
        int pos = atomicAdd(&cur[key], 1);  // LDS atomic only
        pedge[pos] = ((unsigned)sv << BSH) | (unsigned)(dv & (BSZ - 1));
    }
}

// ---------------- stage 2: within-segment sort by dst -> CSR (one-time) ----------------

__global__ __launch_bounds__(512) void subsort(const unsigned* __restrict__ pedge,
                                               const int* __restrict__ chunkStart,
                                               int* __restrict__ pedge2,
                                               int* __restrict__ rowStart,
                                               float* __restrict__ dis) {
    __shared__ unsigned ebuf[CAP];  // 16 KB
    __shared__ int hist[BSZ];
    __shared__ int cur[BSZ];
    __shared__ int deg[BSZ];
    int t = threadIdx.x;
    int b = blockIdx.x;
    deg[t] = 1;  // self loop
    for (int s = 0; s < NCH; ++s) {
        int seg = b * NCH + s;
        int e0 = chunkStart[seg], e1 = chunkStart[seg + 1];
        int n = e1 - e0;
        hist[t] = 0;
        __syncthreads();
        for (int i = t; i < n; i += 512) {
            unsigned p = pedge[e0 + i];
            ebuf[i] = p;
            atomicAdd(&hist[p & (BSZ - 1u)], 1);
        }
        __syncthreads();
        int v = hist[t];
        deg[t] += v;
        cur[t] = v;  // inclusive scan below
        __syncthreads();
        for (int off = 1; off < BSZ; off <<= 1) {
            int add = (t >= off) ? cur[t - off] : 0;
            __syncthreads();
            cur[t] += add;
            __syncthreads();
        }
        int excl = cur[t] - v;
        rowStart[seg * BSZ + t] = e0 + excl;
        cur[t] = excl;
        __syncthreads();
        for (int i = t; i < n; i += 512) {
            unsigned p = ebuf[i];
            int d = p & (BSZ - 1u);
            int pos = atomicAdd(&cur[d], 1);  // 1 int LDS atomic per edge, one-time
            pedge2[e0 + pos] = (int)(p >> BSH);
        }
        __syncthreads();
    }
    int node = (b << BSH) + t;
    if (node < NN) dis[node] = rsqrtf((float)deg[t]);
    if (b == 0 && t == 0) rowStart[NK * BSZ] = NE;
}

// ---------------- dense GEMMs, epilogue-scaled by dis[row] (xs' = (h@W)*dis) ----------------

// LDS-staged: 64 rows/block, coalesced float4 staging, padded stride 132.
#define GXR 64
#define XPAD 132  // floats per row in LDS (128 + 4): 2-way bank alias only
__global__ __launch_bounds__(256) void gemm_x_w1(const float* __restrict__ x,
                                                 const float* __restrict__ W,
                                                 const float* __restrict__ dis,
                                                 float* __restrict__ out) {
    __shared__ float w[DIN * HID];     // 8 KB
    __shared__ float xt[GXR * XPAD];   // 33 KB
    int t = threadIdx.x;
    for (int i = t; i < DIN * HID; i += 256) w[i] = W[i];
    int rbase = blockIdx.x * GXR;  // NN = 3125 * 64, no tail
    const float4* xg = reinterpret_cast<const float4*>(x + (size_t)rbase * DIN);
    float4* xt4 = reinterpret_cast<float4*>(xt);
    for (int i = t; i < GXR * (DIN / 4); i += 256) {
        int row = i >> 5, kk = i & 31;
        xt4[row * (XPAD / 4) + kk] = xg[i];  // fully coalesced global read
    }
    __syncthreads();
    int row = t >> 2;
    int c0 = (t & 3) * 4;
    const float* xr = xt + row * XPAD;
    float ax = 0.f, ay = 0.f, az = 0.f, aw = 0.f;
#pragma unroll 4
    for (int k = 0; k < DIN; ++k) {
        float xv = xr[k];
        float4 wv = *reinterpret_cast<const float4*>(&w[k * HID + c0]);
        ax += xv * wv.x; ay += xv * wv.y; az += xv * wv.z; aw += xv * wv.w;
    }
    int node = rbase + row;
    float dd = dis[node];
    *reinterpret_cast<float4*>(&out[(size_t)node * HID + c0]) =
        make_float4(ax * dd, ay * dd, az * dd, aw * dd);
}

__global__ __launch_bounds__(256) void gemm_h_w16(const float* __restrict__ h,
                                                  const float* __restrict__ W,
                                                  const float* __restrict__ dis,
                                                  float* __restrict__ out) {
    __shared__ float w[HID * HID];
    if (threadIdx.x < HID * HID) w[threadIdx.x] = W[threadIdx.x];
    __syncthreads();
    int row = blockIdx.x * 16 + (threadIdx.x >> 4);
    int c = threadIdx.x & 15;
    if (row >= NN) return;
    const float4* hr = reinterpret_cast<const float4*>(h + (size_t)row * HID);
    float acc = 0.f;
#pragma unroll
    for (int k4 = 0; k4 < HID / 4; ++k4) {
        float4 v = hr[k4];
        acc += v.x * w[(4 * k4 + 0) * HID + c] + v.y * w[(4 * k4 + 1) * HID + c]
             + v.z * w[(4 * k4 + 2) * HID + c] + v.w * w[(4 * k4 + 3) * HID + c];
    }
    out[row * HID + c] = acc * dis[row];
}

__global__ __launch_bounds__(256) void gemm_h_w2(const float* __restrict__ h,
                                                 const float* __restrict__ W,
                                                 const float* __restrict__ dis,
                                                 float* __restrict__ out) {
    int t = blockIdx.x * 256 + threadIdx.x;
    int row = t >> 1;
    int c = t & 1;
    if (row >= NN) return;
    const float* hr = h + (size_t)row * HID;
    float acc = 0.f;
#pragma unroll
    for (int k = 0; k < HID; ++k) acc += hr[k] * W[k * DOUT + c];
    out[row * DOUT + c] = acc * dis[row];
}

// ---------------- aggregation: CSR register accumulation, ZERO atomics ----------------

__global__ __launch_bounds__(1024) void agg16_round(const int* __restrict__ pedge2,
                                                    const int* __restrict__ rowStart,
                                                    const float* __restrict__ xs,
                                                    const float* __restrict__ dis,
                                                    const float* __restrict__ bias,
                                                    float* __restrict__ buf,
                                                    int r, int relu) {
    int t = threadIdx.x;
    int b = blockIdx.x;
    int base = b << BSH;
    int c4 = t & 3;
    int g = t >> 2;  // 256 row-groups
    const int* rs = rowStart + (size_t)(b * NCH + r) * BSZ;
    const float4* xs4 = reinterpret_cast<const float4*>(xs);
    float4* buf4 = reinterpret_cast<float4*>(buf);
    for (int d = g; d < BSZ; d += 256) {
        int e0 = rs[d];
        int e1 = rs[d + 1];  // d=511 reads next segment's start: contiguous layout
        float ax = 0.f, ay = 0.f, az = 0.f, aw = 0.f;
        int e = e0;
        for (; e + 1 < e1; e += 2) {
            int s0 = pedge2[e], s1 = pedge2[e + 1];
            float4 u = xs4[(s0 << 2) + c4];
            float4 w = xs4[(s1 << 2) + c4];
            ax += u.x + w.x; ay += u.y + w.y; az += u.z + w.z; aw += u.w + w.w;
        }
        if (e < e1) {
            float4 u = xs4[(pedge2[e] << 2) + c4];
            ax += u.x; ay += u.y; az += u.z; aw += u.w;
        }
        int node = base + d;
        if (node < NN) {
            int gi = (node << 2) + c4;
            if (r == 0) {  // self-loop row (xs' already has dis[src] factor)
                float4 u = xs4[gi];
                buf4[gi] = make_float4(ax + u.x, ay + u.y, az + u.z, aw + u.w);
            } else if (r < NCH - 1) {
                float4 u = buf4[gi];
                buf4[gi] = make_float4(ax + u.x, ay + u.y, az + u.z, aw + u.w);
            } else {  // epilogue: out = relu(dis[dst]*sum + bias)
                float4 u = buf4[gi];
                float dd = dis[node];
                float4 bb = reinterpret_cast<const float4*>(bias)[c4];
                float vx = dd * (u.x + ax) + bb.x;
                float vy = dd * (u.y + ay) + bb.y;
                float vz = dd * (u.z + az) + bb.z;
                float vw = dd * (u.w + aw) + bb.w;
                if (relu) {
                    vx = fmaxf(vx, 0.f); vy = fmaxf(vy, 0.f);
                    vz = fmaxf(vz, 0.f); vw = fmaxf(vw, 0.f);
                }
                buf4[gi] = make_float4(vx, vy, vz, vw);
            }
        }
    }
}

// conv2: one thread per dst row, float2 registers, fused bias + log_softmax.
__global__ __launch_bounds__(512) void agg2_lsm(const int* __restrict__ pedge2,
                                                const int* __restrict__ rowStart,
                                                const float* __restrict__ xs,
                                                const float* __restrict__ dis,
                                                const float* __restrict__ bias,
                                                float* __restrict__ out) {
    int t = threadIdx.x;
    int b = blockIdx.x;
    int node = (b << BSH) + t;
    if (node >= NN) return;
    const float2* xs2 = reinterpret_cast<const float2*>(xs);
    float a0 = 0.f, a1 = 0.f;
    for (int s = 0; s < NCH; ++s) {
        const int* rs = rowStart + (size_t)(b * NCH + s) * BSZ;
        int e0 = rs[t], e1 = rs[t + 1];
        for (int e = e0; e < e1; ++e) {
            float2 v = xs2[pedge2[e]];
            a0 += v.x; a1 += v.y;
        }
    }
    float2 sv = xs2[node];
    float d = dis[node];
    float v0 = (a0 + sv.x) * d + bias[0];
    float v1 = (a1 + sv.y) * d + bias[1];
    float m = fmaxf(v0, v1);
    float lse = m + logf(__expf(v0 - m) + __expf(v1 - m));
    reinterpret_cast<float2*>(out)[node] = make_float2(v0 - lse, v1 - lse);
}

// ---------------- launch ----------------

extern "C" void kernel_launch(void* const* d_in, const int* in_sizes, int n_in,
                              void* d_out, int out_size, void* d_ws, size_t ws_size,
                              hipStream_t stream) {
    const float* x = (const float*)d_in[0];
    const int* ei = (const int*)d_in[1];
    const float* W1 = (const float*)d_in[2];
    const float* b1 = (const float*)d_in[3];
    const float* W3 = (const float*)d_in[4];
    const float* b3 = (const float*)d_in[5];
    const float* W2 = (const float*)d_in[6];
    const float* b2 = (const float*)d_in[7];
    float* out = (float*)d_out;

    const int* src = ei;       // edge_index[0]
    const int* dst = ei + NE;  // edge_index[1]

    // workspace layout (int elements), ~63 MB total. bufA aliases pedge
    // (pedge is dead after subsort; gemm_x_w1 runs after subsort).
    int* W = (int*)d_ws;
    unsigned* pedge = (unsigned*)W;                        // NE
    int* pedge2 = W + NE;                                  // NE
    int* rowStart = W + 2 * (size_t)NE;                    // NK*BSZ + 4 (pad)
    int* blockHist = rowStart + (size_t)NK * BSZ + 4;      // PB*NK
    int* chunkStart = blockHist + (size_t)PB * NK;         // NK + 4 (pad)
    float* dis = (float*)(chunkStart + NK + 4);            // NN
    float* bufB = dis + NN;                                // NN*HID
    float* bufA = (float*)W;                               // aliases pedge (12.8 <= 20 MB)

    const int B = 256;
    auto cdiv = [](long long a, long long b) { return (int)((a + b - 1) / b); };

    // partition: (bucket,slice) sort -> within-segment dst sort -> CSR + dis
    hist_pass<<<PB, PT, 0, stream>>>(src, dst, blockHist);
    tot_pass<<<cdiv(NK, 256), 256, 0, stream>>>(blockHist, chunkStart);
    scan_keys<<<1, 1024, 0, stream>>>(chunkStart);
    offsets_pass<<<cdiv(NK, 256), 256, 0, stream>>>(blockHist, chunkStart);
    scatter_pass<<<PB, PT, 0, stream>>>(src, dst, blockHist, pedge);
    subsort<<<NB, 512, 0, stream>>>(pedge, chunkStart, pedge2, rowStart, dis);

    // conv1: bufA = (x@W1)*dis ; 8 slice-rounds into bufB (relu+bias in last)
    gemm_x_w1<<<NN / GXR, B, 0, stream>>>(x, W1, dis, bufA);
    for (int r = 0; r < NCH; ++r)
        agg16_round<<<NB, 1024, 0, stream>>>(pedge2, rowStart, bufA, dis, b1, bufB, r, 1);

    // conv3
    gemm_h_w16<<<cdiv(NN, 16), B, 0, stream>>>(bufB, W3, dis, bufA);
    for (int r = 0; r < NCH; ++r)
        agg16_round<<<NB, 1024, 0, stream>>>(pedge2, rowStart, bufA, dis, b3, bufB, r, 1);

    // conv2 + log_softmax
    gemm_h_w2<<<cdiv((long long)NN * DOUT, B), B, 0, stream>>>(bufB, W2, dis, bufA);
    agg2_lsm<<<NB, 512, 0, stream>>>(pedge2, rowStart, bufA, dis, b2, out);
}